// Round 6
// baseline (106.469 us; speedup 1.0000x reference)
//
#include <hip/hip_runtime.h>
#include <math.h>

// Problem constants (from reference): w=0.05, b=5.803, single species.
#define NBINS_MAX 512
#define NMAX      1024                 // atom capacity for LDS staging
#define NFINE_LDS 8192                 // per-block LDS fine-moment grid (32 KB)
#define NSLOT     8                    // u32 slots per coarse bin (32 blocks/slot)
#define SENT32  (NBINS_MAX * NSLOT)    // u32 sentinel index (untouched poison)
constexpr float KW       = 0.05f;
constexpr float INV_KW   = 20.0f;      // 1/w
constexpr float GNORM    = 0.3989422804014327f * INV_KW; // 1/(w*sqrt(2pi))
constexpr float COEFF    = 0.33674809f;    // b*b*0.01
constexpr float FOUR_PI  = 12.566370614359172f;
constexpr float GWIN     = 6.0f * KW;  // gather window +-6 sigma
constexpr float QSCALE     = 1048576.0f;   // 2^20 fixed point for slot flush
constexpr float INV_QSCALE = 1.0f / QSCALE;

// R18: two kernels; LDS ATOMIC COUNT is the lever.
// R15->R16 ablation: exps 10x down, sh_r reads gone, flush halved, tail
// unrolled -> duration UNCHANGED (40.6 vs 42.4). The invariant across all
// slow variants (R15/R16/R17-K1 ~ 22-40us) vs the fast R12-K1: ~12M
// ds_add_f32 LDS atomics (23/pair). Implied cost ~400 cyc/wave-op -- LDS
// f32 atomics are per-lane-serialized RMW, ~2 orders slower than
// ds_read_b32 (5.8 cyc, m134). All counters fit: LDS-pipe stalls are
// invisible to VALUBusy (observed 4-9%), bank-conflict counter barely
// moves, occupancy uniformly low.
// Fix: R12's packed-moment trick PRIVATIZED to LDS.
//  K1: per-block fine grid u32[8192] (delta~1.25e-3), ONE packed ds_add
//      per pair: add = (1<<20) | (eq+4096), eq = rint(e*4096/delta)
//      (|eq|<=2048; low field <= 6144*count, count<=~12/block -> huge
//      margin; count field 12b). 524k LDS atomics total (23x fewer).
//      Then block-local gather fine->coarse: wave w owns coarse bins
//      w, w+8,...; 64 lanes read CONTIGUOUS fine bins (conflict-free
//      ds_read_b32), Gaussian ratio recurrence along each lane's
//      stride-64 samples (2 exp per lane per bin), first-moment
//      correction acc += (c + u*R/w)*exp(-u^2/2)  [R12-verified form].
//      Second-order truncation at delta=1.25e-3: phi-weighted (u^2-1)
//      cancels for smooth density; residual <~1e-5 in G.
//      Flush: 400 u32 fixed-point slot atomics (R17, proven cheap).
//  K2: R17's spectrum kernel verbatim (dispatch boundary = sync;
//      redundant 12.8KB slot rebuild per block; S/F per-q reduce).
// Poison: LDS grids are explicitly zeroed (block-private, exact f32/int);
// global slots use uniform-poison + unsigned wrap vs untouched sentinel.

__global__ void __launch_bounds__(512)
scatter_kernel(const float* __restrict__ pos,
               const float* __restrict__ cell,
               const float* __restrict__ rbins,
               unsigned int* __restrict__ slots,  // [NBINS_MAX*NSLOT] + sentinel
               int N, int nbins)
{
    __shared__ float        sh_pos[3 * NMAX];     // xyz-interleaved positions
    __shared__ unsigned int sh_fm[NFINE_LDS];     // packed count|residual moments
    __shared__ float        sh_coarse[NBINS_MAX]; // per-block coarse KDE result
    const int t  = threadIdx.x;
    const int nb = blockDim.x;             // 512

    // --- stage positions (float4-vectorized), zero fine grid ---
    const int nflt = 3 * N;
    const int nvec = nflt >> 2;
    const float4* p4 = (const float4*)pos;
    for (int v = t; v < nvec; v += nb) {
        const float4 x = p4[v];
        sh_pos[4*v + 0] = x.x;
        sh_pos[4*v + 1] = x.y;
        sh_pos[4*v + 2] = x.z;
        sh_pos[4*v + 3] = x.w;
    }
    for (int s = (nvec << 2) + t; s < nflt; s += nb)
        sh_pos[s] = pos[s];                // tail (absent for N=1024)
    for (int s = t; s < NFINE_LDS; s += nb)
        sh_fm[s] = 0u;                     // exact zero -> no poison handling

    // cell and its inverse (wave-uniform, all threads compute)
    float cm[9];
#pragma unroll
    for (int k = 0; k < 9; ++k) cm[k] = cell[k];
    const float a00 = cm[0], a01 = cm[1], a02 = cm[2];
    const float a10 = cm[3], a11 = cm[4], a12 = cm[5];
    const float a20 = cm[6], a21 = cm[7], a22 = cm[8];
    const float det = a00*(a11*a22 - a12*a21)
                    - a01*(a10*a22 - a12*a20)
                    + a02*(a10*a21 - a11*a20);
    const float id = 1.0f / det;
    float im[9];
    im[0] = (a11*a22 - a12*a21)*id;
    im[1] = (a02*a21 - a01*a22)*id;
    im[2] = (a01*a12 - a02*a11)*id;
    im[3] = (a12*a20 - a10*a22)*id;
    im[4] = (a00*a22 - a02*a20)*id;
    im[5] = (a02*a10 - a00*a12)*id;
    im[6] = (a10*a21 - a11*a20)*id;
    im[7] = (a01*a20 - a00*a21)*id;
    im[8] = (a00*a11 - a01*a10)*id;

    const float r0     = rbins[0];
    const float rend   = rbins[nbins - 1];
    const float minb   = r0   - 3.0f * KW;   // reference's in_win gate
    const float maxb   = rend + 3.0f * KW;
    const float span   = maxb + 0.1f;                      // fine grid [0, span)
    const float fd     = span / (float)NFINE_LDS;          // ~1.26e-3 A
    const float inv_fd = (float)NFINE_LDS / span;
    const float rs     = 4096.0f / fd;                     // residual scale
    const float dr     = (rend - r0) / (float)(nbins - 1); // linspace spacing

    __syncthreads();

    // --- pair phase: TWO row-pairs per block; ONE packed ds_add per pair ---
    const int nrp = (N + 1) / 2;
    const int rp0 = 2 * blockIdx.x;

    auto do_rowpair = [&](int rp) {
        const int A    = rp;
        const int B    = N - 1 - rp;
        const int cntA = N - 1 - A;
        const int cntB = (B != A) ? A : 0;   // guard odd-N center row
        const int tot  = cntA + cntB;
        for (int p = t; p < tot; p += nb) {
            int i, j;
            if (p < cntA) { i = A; j = A + 1 + p; }
            else          { i = B; j = B + 1 + (p - cntA); }

            const float dx = sh_pos[3*j + 0] - sh_pos[3*i + 0];
            const float dy = sh_pos[3*j + 1] - sh_pos[3*i + 1];
            const float dz = sh_pos[3*j + 2] - sh_pos[3*i + 2];
            float fx = dx*im[0] + dy*im[3] + dz*im[6];
            float fy = dx*im[1] + dy*im[4] + dz*im[7];
            float fz = dx*im[2] + dy*im[5] + dz*im[8];
            fx -= rintf(fx); fy -= rintf(fy); fz -= rintf(fz);   // min image
            const float mx = fx*cm[0] + fy*cm[3] + fz*cm[6];
            const float my = fx*cm[1] + fy*cm[4] + fz*cm[7];
            const float mz = fx*cm[2] + fy*cm[5] + fz*cm[8];
            const float d  = sqrtf(mx*mx + my*my + mz*mz + 1e-10f);

            if (d > minb && d < maxb) {
                const int   f  = (int)(d * inv_fd);            // [0, 8192)
                const float e  = d - ((float)f + 0.5f) * fd;   // |e| <= fd/2
                const int   eq = (int)rintf(e * rs);           // |eq| <= 2048
                atomicAdd(&sh_fm[f], (1u << 20) + (unsigned int)(eq + 4096));
            }
        }
    };
    do_rowpair(rp0);
    if (rp0 + 1 < nrp) do_rowpair(rp0 + 1);

    __syncthreads();

    // --- block-local gather: fine moments -> coarse KDE (conflict-free) ---
    // Wave w owns coarse bins w, w+NW, ...; lanes read contiguous fine bins.
    const int   wave  = t >> 6;
    const int   lane  = t & 63;
    const int   nw    = nb >> 6;                     // 8 waves
    const float dstep = 64.0f * fd * INV_KW;         // u-step per lane iter (~1.6)
    const float m2    = __expf(-dstep * dstep);      // recurrence ratio-of-ratio
    const float c1    = fd * INV_KW / 4096.0f;       // Rf -> u*sum(e)/w factor
    const int   wf    = (int)(GWIN * inv_fd) + 1;    // half-window (~239 bins)

    for (int k = wave; k < nbins; k += nw) {
        const float rk = fmaf((float)k, dr, r0);     // == rbins[k] +-1ulp
        const int   fc = (int)(rk * inv_fd);
        int flo = fc - wf; if (flo < 0)             flo = 0;
        int fhi = fc + wf; if (fhi > NFINE_LDS - 1) fhi = NFINE_LDS - 1;
        const int f0 = flo + lane;
        float u = (rk - ((float)f0 + 0.5f) * fd) * INV_KW;
        float e = __expf(-0.5f * u * u);
        float g = __expf(fmaf(u, dstep, -0.5f * dstep * dstep));
        float acc = 0.0f;
        for (int f = f0; f <= fhi; f += 64) {        // contiguous lanes: no conflicts
            const unsigned int v = sh_fm[f];
            const float cf = (float)(v >> 20);                      // count
            const float Rf = (float)((int)(v & 0xFFFFFu)
                                     - (int)((v >> 20) * 4096u));   // sum(e)*rs
            acc = fmaf(fmaf(u * c1, Rf, cf), e, acc);               // (c+uR/w)phi
            u -= dstep; e *= g; g *= m2;             // phi recurrence, 2 mul/iter
        }
#pragma unroll
        for (int off = 32; off > 0; off >>= 1)
            acc += __shfl_down(acc, off, 64);
        if (lane == 0) sh_coarse[k] = acc;
    }
    __syncthreads();

    // --- flush: 400 u32 fixed-point slot atomics, fire-and-forget, END ---
    const int slot = blockIdx.x & (NSLOT - 1);
    for (int k = t; k < nbins; k += nb) {
        const unsigned int q = (unsigned int)rintf(sh_coarse[k] * QSCALE);
        if (q) atomicAdd(&slots[k * NSLOT + slot], q);  // device-scope
    }
    // NO vmcnt wait, NO ticket, NO tail (R12-proven retire pattern).
}

// ---------------------------------------------------------------------------
// K2: every block redundantly rebuilds G (12.8 KB slots, L2-hot), computes
// S,F for its q. Dispatch boundary guarantees visibility -> plain loads.
// ---------------------------------------------------------------------------
__global__ void __launch_bounds__(256)
spectrum_kernel(const unsigned int* __restrict__ slots,
                const float* __restrict__ cell,
                const float* __restrict__ rbins,
                const float* __restrict__ qbins,
                float* __restrict__ out,
                int N, int nbins)
{
    __shared__ float  sh_r[NBINS_MAX];     // exact r_bins (parity with reference)
    __shared__ float2 sh_w2[NBINS_MAX];    // {G -> trapz*r*G, r}
    __shared__ float  sh_red[4];
    const int t = threadIdx.x;

    const unsigned int base = slots[SENT32];   // untouched poison word

    // cell det (wave-uniform)
    const float a00 = cell[0], a01 = cell[1], a02 = cell[2];
    const float a10 = cell[3], a11 = cell[4], a12 = cell[5];
    const float a20 = cell[6], a21 = cell[7], a22 = cell[8];
    const float det = a00*(a11*a22 - a12*a21)
                    - a01*(a10*a22 - a12*a20)
                    + a02*(a10*a21 - a11*a20);
    const float vol     = fabsf(det);
    const float n_pairs = 0.5f * (float)N * (float)(N - 1);
    const float rho     = (float)N / vol;
    const float pref    = (vol / n_pairs) * GNORM;

    // --- pass 1: slots -> G (each block redundantly; 2 uint4 loads/bin) ---
    const uint4* s4 = (const uint4*)slots;
    for (int k = t; k < nbins; k += 256) {
        const uint4 aa = s4[2*k + 0];
        const uint4 bb = s4[2*k + 1];
        unsigned long long tot = 0;                  // exact: per-slot < 2^32
        tot += (unsigned long long)(aa.x - base);    // unsigned wrap vs poison
        tot += (unsigned long long)(aa.y - base);
        tot += (unsigned long long)(aa.z - base);
        tot += (unsigned long long)(aa.w - base);
        tot += (unsigned long long)(bb.x - base);
        tot += (unsigned long long)(bb.y - base);
        tot += (unsigned long long)(bb.z - base);
        tot += (unsigned long long)(bb.w - base);
        const float summed = (float)tot * INV_QSCALE;
        const float rk = rbins[k];
        const float g  = pref * summed / (FOUR_PI * rk * rk);
        const float G  = COEFF * (g - 1.0f);
        if (blockIdx.x == 0) out[k] = G;             // single writer for G(r)
        sh_r[k]  = rk;
        sh_w2[k] = make_float2(G, rk);
    }
    __syncthreads();

    // --- pass 2: G -> trapezoid weight * r * G (needs neighbor r) ---
    for (int k = t; k < nbins; k += 256) {
        const float rk   = sh_r[k];
        const float w_lo = (k > 0)         ? (rk - sh_r[k - 1]) : 0.0f;
        const float w_hi = (k < nbins - 1) ? (sh_r[k + 1] - rk) : 0.0f;
        sh_w2[k].x = 0.5f * (w_lo + w_hi) * rk * sh_w2[k].x;
    }
    __syncthreads();

    // --- S(Q), F(Q) for q = qbins[blockIdx.x]: 400-term LDS-hot reduce ---
    const int   qi   = blockIdx.x;
    const float q    = qbins[qi];
    const float qinv = 1.0f / (q + 1e-10f);
    float acc = 0.0f;
    for (int k = t; k < nbins; k += 256) {
        const float2 v = sh_w2[k];
        acc += v.x * __sinf(q * v.y);
    }
#pragma unroll
    for (int off = 32; off > 0; off >>= 1)
        acc += __shfl_down(acc, off, 64);
    if ((t & 63) == 0) sh_red[t >> 6] = acc;
    __syncthreads();
    if (t == 0) {
        const float S = 1.0f + FOUR_PI * rho * qinv *
                        (sh_red[0] + sh_red[1] + sh_red[2] + sh_red[3]);
        out[nbins + qi]     = S;               // S(Q)
        out[2 * nbins + qi] = q * (S - 1.0f);  // F(Q)
    }
}

// ---------------------------------------------------------------------------
extern "C" void kernel_launch(void* const* d_in, const int* in_sizes, int n_in,
                              void* d_out, int out_size, void* d_ws, size_t ws_size,
                              hipStream_t stream)
{
    const float* pos   = (const float*)d_in[0];  // (N,3) f32
    const float* cell  = (const float*)d_in[1];  // (3,3) f32
    const float* rbins = (const float*)d_in[2];  // (nbins,) f32
    const float* qbins = (const float*)d_in[3];  // (nbins,) f32
    float* out = (float*)d_out;                  // (3, nbins) f32

    const int N     = in_sizes[0] / 3;
    const int nbins = in_sizes[2];
    const int nrp   = (N + 1) / 2;               // row-pairs
    const int grid1 = (nrp + 1) / 2;             // 2 row-pairs per block -> 256

    unsigned int* slots = (unsigned int*)d_ws;   // [NBINS_MAX*NSLOT] + sentinel

    hipLaunchKernelGGL(scatter_kernel, dim3(grid1), dim3(512), 0, stream,
                       pos, cell, rbins, slots, N, nbins);
    hipLaunchKernelGGL(spectrum_kernel, dim3(nbins), dim3(256), 0, stream,
                       slots, cell, rbins, qbins, out, N, nbins);
}

// Round 7
// 76.567 us; speedup vs baseline: 1.3905x; 1.3905x over previous
//
#include <hip/hip_runtime.h>
#include <math.h>

// Problem constants (from reference): w=0.05, b=5.803, single species.
#define NBINS_MAX 512
#define NMAX      1024                 // atom capacity for LDS staging
#define NFG       2048                 // per-block LDS fine moment grid (u64, 16 KB)
#define GOFF      64                   // fine-grid index offset (covers d < r0)
#define WHALF     49                   // gather half-window in fine bins (6.08 sigma)
#define NSLOT     8                    // u32 slots per coarse bin (32 blocks/slot)
#define SENT32  (NBINS_MAX * NSLOT)    // u32 sentinel index (untouched poison)
constexpr float KW       = 0.05f;
constexpr float INV_KW   = 20.0f;      // 1/w
constexpr float GNORM    = 0.3989422804014327f * INV_KW; // 1/(w*sqrt(2pi))
constexpr float COEFF    = 0.33674809f;    // b*b*0.01
constexpr float FOUR_PI  = 12.566370614359172f;
constexpr float QSCALE     = 1048576.0f;   // 2^20 fixed point for slot flush
constexpr float INV_QSCALE = 1.0f / QSCALE;
constexpr float ES  = 33554432.0f;     // 2^25: M1 (sum e) fixed-point scale
constexpr float E2S = 536870912.0f;    // 2^29: M2 (sum e^2) fixed-point scale
constexpr float A1  = INV_KW / ES;             // m1 -> (sum e)/w factor
constexpr float A2  = 0.5f * INV_KW * INV_KW / E2S;  // m2 -> (sum e^2)/(2w^2)

// R19: two kernels; SECOND-MOMENT correction buys a 5x coarser fine grid.
// R18 post-mortem: K1=51us, VALUBusy 47% -- genuinely VALU-bound on the
// per-block gather (window +-478 fine bins at delta=1.26e-3, x400 bins,
// x256 redundant blocks ~ 1.3G lane-ops ~ 16us min + latency). delta was
// pinned by FIRST-moment accuracy (empirical absmax ~ delta^2: 1.2e-4 at
// 1.26e-3). Adding M2=sum(e^2) computes the delta^2 term exactly; residual
// is O(delta^4) (odd orders cancel, 4th ~ (delta/2w)^4/80 ~ 1.5e-5 rel at
// delta=dr/4=6.2e-3). Gather window shrinks to +-49 -> 9.7x less work.
//  K1: per pair ONE ds_add_u64 into a phase-interleaved [4][512] u64 grid
//      (addr = (gi&3)*512 + gi/4). Packed [count:12 @52][sum e2q:23 @29]
//      [sum(eq+2^17):29 @0]; per-block <=~10 pairs/fine-bin -> >=100x field
//      margins. Gather: each LANE owns one coarse bin k (no shfl reduce);
//      iteration it: gi=4k+GOFF-WHALF+it -> phase wave-uniform, q=k+const
//      contiguous -> conflict-free ds_read_b64; 99 static iterations with
//      data-independent addresses (compiler pipelines); Gaussian ratio
//      recurrence (2 exps/lane); flush = 1 u32 slot atomic from register.
//  K2: R17's spectrum kernel, slot deltas now SIGN-extended (acc may be
//      slightly negative via the phi'' term; two's-complement wrap is exact).
// Correction formula (Taylor of phi((rk-d)/w) at bin center, u=(rk-cf)/w):
//   summed[k] = sum_f phi(u)*[count + u*(sum e)/w + (u^2-1)*(sum e^2)/(2w^2)]
// Poison: LDS grid explicitly zeroed; global slots use uniform-poison +
// unsigned wrap vs untouched sentinel (R12 trick, proven R15-R18).

__global__ void __launch_bounds__(512)
scatter_kernel(const float* __restrict__ pos,
               const float* __restrict__ cell,
               const float* __restrict__ rbins,
               unsigned int* __restrict__ slots,  // [NBINS_MAX*NSLOT] + sentinel
               int N, int nbins)
{
    __shared__ float sh_pos[3 * NMAX];            // xyz-interleaved positions
    __shared__ unsigned long long sh_fm[NFG];     // packed moments, [4][512] interleave
    const int t  = threadIdx.x;
    const int nb = blockDim.x;             // 512

    // --- stage positions (float4-vectorized), zero fine grid ---
    const int nflt = 3 * N;
    const int nvec = nflt >> 2;
    const float4* p4 = (const float4*)pos;
    for (int v = t; v < nvec; v += nb) {
        const float4 x = p4[v];
        sh_pos[4*v + 0] = x.x;
        sh_pos[4*v + 1] = x.y;
        sh_pos[4*v + 2] = x.z;
        sh_pos[4*v + 3] = x.w;
    }
    for (int s = (nvec << 2) + t; s < nflt; s += nb)
        sh_pos[s] = pos[s];                // tail (absent for N=1024)
    for (int s = t; s < NFG; s += nb)
        sh_fm[s] = 0ull;                   // exact zero -> no poison handling

    // cell and its inverse (wave-uniform, all threads compute)
    float cm[9];
#pragma unroll
    for (int k = 0; k < 9; ++k) cm[k] = cell[k];
    const float a00 = cm[0], a01 = cm[1], a02 = cm[2];
    const float a10 = cm[3], a11 = cm[4], a12 = cm[5];
    const float a20 = cm[6], a21 = cm[7], a22 = cm[8];
    const float det = a00*(a11*a22 - a12*a21)
                    - a01*(a10*a22 - a12*a20)
                    + a02*(a10*a21 - a11*a20);
    const float id = 1.0f / det;
    float im[9];
    im[0] = (a11*a22 - a12*a21)*id;
    im[1] = (a02*a21 - a01*a22)*id;
    im[2] = (a01*a12 - a02*a11)*id;
    im[3] = (a12*a20 - a10*a22)*id;
    im[4] = (a00*a22 - a02*a20)*id;
    im[5] = (a02*a10 - a00*a12)*id;
    im[6] = (a10*a21 - a11*a20)*id;
    im[7] = (a01*a20 - a00*a21)*id;
    im[8] = (a00*a11 - a01*a10)*id;

    const float r0     = rbins[0];
    const float rend   = rbins[nbins - 1];
    const float minb   = r0   - 3.0f * KW;   // reference's in_win gate
    const float maxb   = rend + 3.0f * KW;
    const float dr     = (rend - r0) / (float)(nbins - 1); // linspace spacing
    const float fdelta = 0.25f * dr;                       // fine grid: dr/4
    const float inv_fd = 1.0f / fdelta;

    __syncthreads();

    // --- pair phase: TWO row-pairs per block; ONE ds_add_u64 per pair ---
    const int nrp = (N + 1) / 2;
    const int rp0 = 2 * blockIdx.x;

    auto do_rowpair = [&](int rp) {
        const int A    = rp;
        const int B    = N - 1 - rp;
        const int cntA = N - 1 - A;
        const int cntB = (B != A) ? A : 0;   // guard odd-N center row
        const int tot  = cntA + cntB;
        for (int p = t; p < tot; p += nb) {
            int i, j;
            if (p < cntA) { i = A; j = A + 1 + p; }
            else          { i = B; j = B + 1 + (p - cntA); }

            const float dx = sh_pos[3*j + 0] - sh_pos[3*i + 0];
            const float dy = sh_pos[3*j + 1] - sh_pos[3*i + 1];
            const float dz = sh_pos[3*j + 2] - sh_pos[3*i + 2];
            float fx = dx*im[0] + dy*im[3] + dz*im[6];
            float fy = dx*im[1] + dy*im[4] + dz*im[7];
            float fz = dx*im[2] + dy*im[5] + dz*im[8];
            fx -= rintf(fx); fy -= rintf(fy); fz -= rintf(fz);   // min image
            const float mx = fx*cm[0] + fy*cm[3] + fz*cm[6];
            const float my = fx*cm[1] + fy*cm[4] + fz*cm[7];
            const float mz = fx*cm[2] + fy*cm[5] + fz*cm[8];
            const float d  = sqrtf(mx*mx + my*my + mz*mz + 1e-10f);

            if (d > minb && d < maxb) {
                const int   gi = (int)rintf((d - r0) * inv_fd) + GOFF; // [40,1684]
                const float e  = d - fmaf((float)(gi - GOFF), fdelta, r0); // |e|<=fd/2
                const int   eq  = (int)rintf(e * ES);            // |eq| <= ~104k
                const unsigned int e2q = (unsigned int)rintf(e * e * E2S); // <= ~5.2k
                const unsigned long long val =
                      (1ull << 52)
                    | ((unsigned long long)e2q << 29)
                    | (unsigned long long)(unsigned int)(eq + 131072);
                const int addr = ((gi & 3) << 9) | (gi >> 2);    // [4][512] interleave
                atomicAdd(&sh_fm[addr], val);                    // ds_add_u64
            }
        }
    };
    do_rowpair(rp0);
    if (rp0 + 1 < nrp) do_rowpair(rp0 + 1);

    __syncthreads();

    // --- gather: lane t owns coarse bin k=t; conflict-free ds_read_b64 ---
    if (t < nbins && t < 484) {            // 4k+GOFF+WHALF < NFG guard
        const int   k  = t;
        const float dw = fdelta * INV_KW;  // u-step per fine bin (~0.124)
        float u = (float)WHALF * dw;       // 6.08 sigma, walks down
        float e = __expf(-0.5f * u * u);
        float g = __expf(fmaf(u, dw, -0.5f * dw * dw));  // phi-step ratio
        const float m = __expf(-dw * dw);                // ratio-of-ratio
        float acc = 0.0f;
        const int gbase = 4 * k + GOFF - WHALF;
#pragma unroll 4
        for (int it = 0; it <= 2 * WHALF; ++it) {
            const int gi   = gbase + it;
            const int addr = ((gi & 3) << 9) | (gi >> 2);
            const unsigned long long v = sh_fm[addr];
            const unsigned int cntu = (unsigned int)(v >> 52);
            const float cnt = (float)cntu;
            const float m2  = (float)(unsigned int)((v >> 29) & 0x7FFFFFu);
            const float m1  = (float)((int)((unsigned int)v & 0x1FFFFFFFu)
                                      - (int)(cntu << 17));
            const float term = fmaf(u * A1, m1,
                               fmaf(fmaf(u, u, -1.0f) * A2, m2, cnt));
            acc = fmaf(term, e, acc);
            e *= g; g *= m;                // phi recurrence (2 mul/iter)
            u -= dw;
        }
        // flush straight from register: one u32 slot atomic per bin.
        // acc may be slightly NEGATIVE (phi'' term) -> signed fixed point;
        // two's-complement wrap is exact under addition.
        const int slot = blockIdx.x & (NSLOT - 1);
        const int q = (int)rintf(acc * QSCALE);
        if (q) atomicAdd(&slots[k * NSLOT + slot], (unsigned int)q);
    }
    // NO vmcnt wait, NO ticket, NO tail (R12-proven retire pattern).
}

// ---------------------------------------------------------------------------
// K2: every block redundantly rebuilds G (12.8 KB slots, L2-hot), computes
// S,F for its q. Dispatch boundary guarantees visibility -> plain loads.
// Slot deltas SIGN-extended (see R19 note above).
// ---------------------------------------------------------------------------
__global__ void __launch_bounds__(256)
spectrum_kernel(const unsigned int* __restrict__ slots,
                const float* __restrict__ cell,
                const float* __restrict__ rbins,
                const float* __restrict__ qbins,
                float* __restrict__ out,
                int N, int nbins)
{
    __shared__ float  sh_r[NBINS_MAX];     // exact r_bins (parity with reference)
    __shared__ float2 sh_w2[NBINS_MAX];    // {G -> trapz*r*G, r}
    __shared__ float  sh_red[4];
    const int t = threadIdx.x;

    const unsigned int base = slots[SENT32];   // untouched poison word

    // cell det (wave-uniform)
    const float a00 = cell[0], a01 = cell[1], a02 = cell[2];
    const float a10 = cell[3], a11 = cell[4], a12 = cell[5];
    const float a20 = cell[6], a21 = cell[7], a22 = cell[8];
    const float det = a00*(a11*a22 - a12*a21)
                    - a01*(a10*a22 - a12*a20)
                    + a02*(a10*a21 - a11*a20);
    const float vol     = fabsf(det);
    const float n_pairs = 0.5f * (float)N * (float)(N - 1);
    const float rho     = (float)N / vol;
    const float pref    = (vol / n_pairs) * GNORM;

    // --- pass 1: slots -> G (each block redundantly; 2 uint4 loads/bin) ---
    const uint4* s4 = (const uint4*)slots;
    for (int k = t; k < nbins; k += 256) {
        const uint4 aa = s4[2*k + 0];
        const uint4 bb = s4[2*k + 1];
        long long tot = 0;                           // signed, exact
        tot += (int)(aa.x - base);                   // unsigned wrap, then sign
        tot += (int)(aa.y - base);
        tot += (int)(aa.z - base);
        tot += (int)(aa.w - base);
        tot += (int)(bb.x - base);
        tot += (int)(bb.y - base);
        tot += (int)(bb.z - base);
        tot += (int)(bb.w - base);
        const float summed = (float)tot * INV_QSCALE;
        const float rk = rbins[k];
        const float g  = pref * summed / (FOUR_PI * rk * rk);
        const float G  = COEFF * (g - 1.0f);
        if (blockIdx.x == 0) out[k] = G;             // single writer for G(r)
        sh_r[k]  = rk;
        sh_w2[k] = make_float2(G, rk);
    }
    __syncthreads();

    // --- pass 2: G -> trapezoid weight * r * G (needs neighbor r) ---
    for (int k = t; k < nbins; k += 256) {
        const float rk   = sh_r[k];
        const float w_lo = (k > 0)         ? (rk - sh_r[k - 1]) : 0.0f;
        const float w_hi = (k < nbins - 1) ? (sh_r[k + 1] - rk) : 0.0f;
        sh_w2[k].x = 0.5f * (w_lo + w_hi) * rk * sh_w2[k].x;
    }
    __syncthreads();

    // --- S(Q), F(Q) for q = qbins[blockIdx.x]: 400-term LDS-hot reduce ---
    const int   qi   = blockIdx.x;
    const float q    = qbins[qi];
    const float qinv = 1.0f / (q + 1e-10f);
    float acc = 0.0f;
    for (int k = t; k < nbins; k += 256) {
        const float2 v = sh_w2[k];
        acc += v.x * __sinf(q * v.y);
    }
#pragma unroll
    for (int off = 32; off > 0; off >>= 1)
        acc += __shfl_down(acc, off, 64);
    if ((t & 63) == 0) sh_red[t >> 6] = acc;
    __syncthreads();
    if (t == 0) {
        const float S = 1.0f + FOUR_PI * rho * qinv *
                        (sh_red[0] + sh_red[1] + sh_red[2] + sh_red[3]);
        out[nbins + qi]     = S;               // S(Q)
        out[2 * nbins + qi] = q * (S - 1.0f);  // F(Q)
    }
}

// ---------------------------------------------------------------------------
extern "C" void kernel_launch(void* const* d_in, const int* in_sizes, int n_in,
                              void* d_out, int out_size, void* d_ws, size_t ws_size,
                              hipStream_t stream)
{
    const float* pos   = (const float*)d_in[0];  // (N,3) f32
    const float* cell  = (const float*)d_in[1];  // (3,3) f32
    const float* rbins = (const float*)d_in[2];  // (nbins,) f32
    const float* qbins = (const float*)d_in[3];  // (nbins,) f32
    float* out = (float*)d_out;                  // (3, nbins) f32

    const int N     = in_sizes[0] / 3;
    const int nbins = in_sizes[2];
    const int nrp   = (N + 1) / 2;               // row-pairs
    const int grid1 = (nrp + 1) / 2;             // 2 row-pairs per block -> 256

    unsigned int* slots = (unsigned int*)d_ws;   // [NBINS_MAX*NSLOT] + sentinel

    hipLaunchKernelGGL(scatter_kernel, dim3(grid1), dim3(512), 0, stream,
                       pos, cell, rbins, slots, N, nbins);
    hipLaunchKernelGGL(spectrum_kernel, dim3(nbins), dim3(256), 0, stream,
                       slots, cell, rbins, qbins, out, N, nbins);
}